// Round 9
// baseline (378.043 us; speedup 1.0000x reference)
//
#include <hip/hip_runtime.h>
#include <stdint.h>

#define Bx   2
#define Sx   2048
#define Dx   1024
#define Hx   16
#define DKx  64
#define DFFx 4096
#define Mx   4096   // B*S

#define CEXP 0.18033688011112042f   // log2(e)/sqrt(64), folded into Q at QKV epilogue

typedef __attribute__((ext_vector_type(8))) short short8;
typedef __attribute__((ext_vector_type(4))) float f32x4;
typedef __attribute__((ext_vector_type(4))) unsigned short ushort4v;

__device__ __forceinline__ unsigned short f2b(float f) {
    union { float f; uint32_t u; } v; v.f = f;
    uint32_t u = v.u;
    u += 0x7fffu + ((u >> 16) & 1u);   // RNE
    return (unsigned short)(u >> 16);
}

__device__ __forceinline__ float fexp2(float x) {
#if __has_builtin(__builtin_amdgcn_exp2f)
    return __builtin_amdgcn_exp2f(x);
#else
    return exp2f(x);
#endif
}

// ---------------- fused weight convert (6 weights) + QKV bias concat ----------------
__global__ __launch_bounds__(256) void conv_all(
    const float4* __restrict__ wq, const float4* __restrict__ wk,
    const float4* __restrict__ wv, const float4* __restrict__ wo,
    const float4* __restrict__ w1, const float4* __restrict__ w2,
    const float4* __restrict__ bq, const float4* __restrict__ bk,
    const float4* __restrict__ bv,
    ushort4v* __restrict__ dqkv, ushort4v* __restrict__ dwo,
    ushort4v* __restrict__ d1, ushort4v* __restrict__ d2,
    float4* __restrict__ dbias) {
    const int i = blockIdx.x * 256 + threadIdx.x;
    const int S4 = 1 << 18;                    // 1024*1024/4
    if (i < 4 * S4) {
        const float4* s; ushort4v* d;
        if (i < S4)          { s = wq + i;            d = dqkv + i; }
        else if (i < 2 * S4) { s = wk + (i - S4);     d = dqkv + i; }
        else if (i < 3 * S4) { s = wv + (i - 2 * S4); d = dqkv + i; }
        else                 { s = wo + (i - 3 * S4); d = dwo + (i - 3 * S4); }
        const float4 v = *s;
        ushort4v o; o.x = f2b(v.x); o.y = f2b(v.y); o.z = f2b(v.z); o.w = f2b(v.w);
        *d = o;
    } else if (i < 8 * S4) {
        const float4 v = w1[i - 4 * S4];
        ushort4v o; o.x = f2b(v.x); o.y = f2b(v.y); o.z = f2b(v.z); o.w = f2b(v.w);
        d1[i - 4 * S4] = o;
    } else if (i < 12 * S4) {
        const float4 v = w2[i - 8 * S4];
        ushort4v o; o.x = f2b(v.x); o.y = f2b(v.y); o.z = f2b(v.z); o.w = f2b(v.w);
        d2[i - 8 * S4] = o;
    } else if (i < 12 * S4 + 768) {
        const int jn = i - 12 * S4;
        dbias[jn] = (jn < 256) ? bq[jn] : (jn < 512 ? bk[jn - 256] : bv[jn - 512]);
    }
}

// ---------------- LayerNorm: ddof=1, alpha*(x-mean)/(std+eps)+bias ----------------
__global__ __launch_bounds__(256) void layernorm_k(const float* __restrict__ x,
                                                   const float* __restrict__ alpha,
                                                   const float* __restrict__ beta,
                                                   unsigned short* __restrict__ out) {
    __shared__ float red[8];
    const int row = blockIdx.x;
    const int t = threadIdx.x, lane = t & 63, w = t >> 6;
    float4 v = ((const float4*)(x + (size_t)row * Dx))[t];
    float s = v.x + v.y + v.z + v.w;
    float q = v.x*v.x + v.y*v.y + v.z*v.z + v.w*v.w;
#pragma unroll
    for (int off = 1; off < 64; off <<= 1) {
        s += __shfl_xor(s, off);
        q += __shfl_xor(q, off);
    }
    if (lane == 0) { red[w] = s; red[4 + w] = q; }
    __syncthreads();
    s = red[0] + red[1] + red[2] + red[3];
    q = red[4] + red[5] + red[6] + red[7];
    const float mean = s * (1.0f / Dx);
    float var = (q - (float)Dx * mean * mean) * (1.0f / (Dx - 1));
    var = fmaxf(var, 0.0f);
    const float inv = alpha[0] / (sqrtf(var) + 1e-5f);
    const float bb = beta[0];
    ushort4v o;
    o.x = f2b((v.x - mean) * inv + bb);
    o.y = f2b((v.y - mean) * inv + bb);
    o.z = f2b((v.z - mean) * inv + bb);
    o.w = f2b((v.w - mean) * inv + bb);
    *(ushort4v*)(out + (size_t)row * Dx + t * 4) = o;
}

#define GLDS(gp, lp) __builtin_amdgcn_global_load_lds( \
    (const __attribute__((address_space(1))) unsigned int*)(gp), \
    (__attribute__((address_space(3))) unsigned int*)(lp), 16, 0, 0)

#define STAGE(buf, kt) do {                                                     \
    const int k0_ = (kt) << 5;                                                  \
    _Pragma("unroll")                                                           \
    for (int i_ = 0; i_ < MB/2; ++i_) {                                         \
      const int ca_ = (MB==4) ? (w*2 + i_) : w;                                 \
      GLDS(A + (size_t)(bm + ca_*16 + srow)*K + k0_ + skc*8, &As[buf][ca_*512]);\
    }                                                                           \
    _Pragma("unroll")                                                           \
    for (int i_ = 0; i_ < 2; ++i_) {                                            \
      const int cb_ = w*2 + i_;                                                 \
      GLDS(W + (size_t)(bn + cb_*16 + srow)*K + k0_ + skc*8, &Bs[buf][cb_*512]);\
    }                                                                           \
  } while (0)

// ---------------- O-proj GEMM: BM=64, 1D XCD-grouped grid of 512 ----------------
// out f32 = A*W^T + bias + res   (swapped-operand MFMA -> float4 stores)
template<int BM>
__global__ __launch_bounds__(256) void gemm2(const short* __restrict__ A,
                                             const short* __restrict__ W,
                                             const float* __restrict__ bias,
                                             const float* __restrict__ res,
                                             float* __restrict__ Cout,
                                             int M, int N, int K) {
    constexpr int MB = BM / 32;
    __shared__ alignas(16) short As[2][BM * 32];
    __shared__ alignas(16) short Bs[2][128 * 32];
    const int t = threadIdx.x, lane = t & 63, w = t >> 6;
    const int lo = lane & 15, hi = lane >> 4;
    // XCD-grouped: 8 bn-blocks sharing an A-panel land on one XCD
    const int bb = blockIdx.x, xcd = bb & 7, jj = bb >> 3;
    const int bn = (jj & 7) * 128;
    const int bm = (xcd * 8 + (jj >> 3)) * BM;
    const int wm = (w >> 1) * (BM / 2), wn = (w & 1) * 64;
    const int srow = lane >> 2, skc = lane & 3;

    f32x4 acc[MB][4] = {};
    const int nkt = K >> 5;

    STAGE(0, 0);
    __syncthreads();
    int cur = 0;
    for (int kt = 0; kt < nkt; ++kt) {
        if (kt + 1 < nkt) STAGE(cur ^ 1, kt + 1);
        const short* as = &As[cur][0];
        const short* bs = &Bs[cur][0];
        short8 af[MB], bfr[4];
#pragma unroll
        for (int mb = 0; mb < MB; ++mb)
            af[mb] = *(const short8*)&as[(wm + mb * 16 + lo) * 32 + hi * 8];
#pragma unroll
        for (int nb = 0; nb < 4; ++nb)
            bfr[nb] = *(const short8*)&bs[(wn + nb * 16 + lo) * 32 + hi * 8];
#pragma unroll
        for (int mb = 0; mb < MB; ++mb)
#pragma unroll
            for (int nb = 0; nb < 4; ++nb)   // swapped: lane regs = 4 consecutive n
                acc[mb][nb] = __builtin_amdgcn_mfma_f32_16x16x32_bf16(bfr[nb], af[mb], acc[mb][nb], 0, 0, 0);
        __syncthreads();
        cur ^= 1;
    }

#pragma unroll
    for (int mb = 0; mb < MB; ++mb)
#pragma unroll
        for (int nb = 0; nb < 4; ++nb) {
            const int row = bm + wm + mb * 16 + lo;
            const int col0 = bn + wn + nb * 16 + hi * 4;
            const float4 bv4 = *(const float4*)&bias[col0];
            const size_t idx = (size_t)row * N + col0;
            const float4 rs4 = *(const float4*)&res[idx];
            float4 o4;
            o4.x = acc[mb][nb][0] + bv4.x + rs4.x;
            o4.y = acc[mb][nb][1] + bv4.y + rs4.y;
            o4.z = acc[mb][nb][2] + bv4.z + rs4.z;
            o4.w = acc[mb][nb][3] + bv4.w + rs4.w;
            *(float4*)&Cout[idx] = o4;
        }
}

// ---------------- 256x256 8-wave 2-phase GEMM, BK=32, XCD-grouped 1D grid ----------------
// MODE 0: bf16 out (ushort4 stores). MODE 2: QKV split (Q scaled, K row-major; V -> V^T).
#define STG256(buf, kt) do {                                                     \
    const int k0_ = (kt) << 5;                                                   \
    _Pragma("unroll")                                                            \
    for (int i_ = 0; i_ < 2; ++i_) {                                             \
      const int c_ = i_ * 8 + w;                                                 \
      GLDS(A + (size_t)(bm + c_*16 + (lane>>2))*K + k0_ + (lane&3)*8,            \
           &As[buf][c_*512]);                                                    \
      GLDS(W + (size_t)(bn + c_*16 + (lane>>2))*K + k0_ + (lane&3)*8,            \
           &Bs[buf][c_*512]);                                                    \
    }                                                                            \
  } while (0)

template<int MODE>
__global__ __launch_bounds__(512, 2) void gemm256(const short* __restrict__ A,
                                                  const short* __restrict__ W,
                                                  const float* __restrict__ bias,
                                                  void* __restrict__ Cout,
                                                  int M, int N, int K,
                                                  int nbn, int rpx,
                                                  unsigned short* __restrict__ Qout,
                                                  unsigned short* __restrict__ Kout,
                                                  unsigned short* __restrict__ Vout) {
    __shared__ alignas(16) short As[2][256 * 32];
    __shared__ alignas(16) short Bs[2][256 * 32];
    const int t = threadIdx.x, lane = t & 63, w = t >> 6;
    const int lo = lane & 15, hi = lane >> 4;
    const int bb = blockIdx.x, xcd = bb & 7, jj = bb >> 3;
    const int bm = (xcd * rpx + jj / nbn) * 256;
    const int bn = (jj % nbn) * 256;
    const int wr = w >> 2, wc = w & 3;          // 2 x 4 wave grid; per-wave 128 x 64 out

    f32x4 acc[8][4] = {};
    const int nkt = K >> 5;

    STG256(0, 0);
    __syncthreads();
    int cur = 0;
    for (int kt = 0; kt < nkt; ++kt) {
        if (kt + 1 < nkt) STG256(cur ^ 1, kt + 1);
        const short* as = &As[cur][0];
        const short* bs = &Bs[cur][0];
        short8 bfr[4];
#pragma unroll
        for (int nb = 0; nb < 4; ++nb)
            bfr[nb] = *(const short8*)&bs[(wc * 64 + nb * 16 + lo) * 32 + hi * 8];
#pragma unroll
        for (int mh = 0; mh < 2; ++mh) {
            short8 af[4];
#pragma unroll
            for (int mb = 0; mb < 4; ++mb)
                af[mb] = *(const short8*)&as[(wr * 128 + mh * 64 + mb * 16 + lo) * 32 + hi * 8];
#pragma unroll
            for (int mb = 0; mb < 4; ++mb)
#pragma unroll
                for (int nb = 0; nb < 4; ++nb)   // swapped operands
                    acc[mh * 4 + mb][nb] =
                        __builtin_amdgcn_mfma_f32_16x16x32_bf16(bfr[nb], af[mb], acc[mh * 4 + mb][nb], 0, 0, 0);
        }
        __syncthreads();
        cur ^= 1;
    }

#pragma unroll
    for (int mb = 0; mb < 8; ++mb)
#pragma unroll
        for (int nb = 0; nb < 4; ++nb) {
            const int row = bm + wr * 128 + mb * 16 + lo;
            const int col0 = bn + wc * 64 + nb * 16 + hi * 4;
            const float4 bv4 = *(const float4*)&bias[col0];
            if (MODE == 0) {
                ushort4v pv;
                pv.x = f2b(acc[mb][nb][0] + bv4.x);
                pv.y = f2b(acc[mb][nb][1] + bv4.y);
                pv.z = f2b(acc[mb][nb][2] + bv4.z);
                pv.w = f2b(acc[mb][nb][3] + bv4.w);
                *(ushort4v*)&((unsigned short*)Cout)[(size_t)row * N + col0] = pv;
            } else {
                if (col0 < 1024) {         // Q, pre-scaled by CEXP (softmax fold)
                    ushort4v pv;
                    pv.x = f2b((acc[mb][nb][0] + bv4.x) * CEXP);
                    pv.y = f2b((acc[mb][nb][1] + bv4.y) * CEXP);
                    pv.z = f2b((acc[mb][nb][2] + bv4.z) * CEXP);
                    pv.w = f2b((acc[mb][nb][3] + bv4.w) * CEXP);
                    *(ushort4v*)&Qout[(size_t)row * 1024 + col0] = pv;
                } else if (col0 < 2048) {
                    ushort4v pv;
                    pv.x = f2b(acc[mb][nb][0] + bv4.x);
                    pv.y = f2b(acc[mb][nb][1] + bv4.y);
                    pv.z = f2b(acc[mb][nb][2] + bv4.z);
                    pv.w = f2b(acc[mb][nb][3] + bv4.w);
                    *(ushort4v*)&Kout[(size_t)row * 1024 + (col0 - 1024)] = pv;
                } else {
                    const int bbv = row >> 11, s0 = row & 2047;
#pragma unroll
                    for (int j = 0; j < 4; ++j) {
                        const int dk = col0 - 2048 + j;
                        const int vrow = (bbv * 16 + (dk >> 6)) * 64 + (dk & 63);
                        Vout[(size_t)vrow * Sx + s0] = f2b(acc[mb][nb][j] + ((const float*)&bv4)[j]);
                    }
                }
            }
        }
}

// ---------------- FFN2 split-K GEMM: 128x128, KZ=2, XCD-grouped 1D grid of 512 ----------------
__global__ __launch_bounds__(256) void gemmsk(const short* __restrict__ A,
                                              const short* __restrict__ W,
                                              float* __restrict__ P0,
                                              float* __restrict__ P1,
                                              int K) {
    constexpr int MB = 4;
    __shared__ alignas(16) short As[2][128 * 32];
    __shared__ alignas(16) short Bs[2][128 * 32];
    const int t = threadIdx.x, lane = t & 63, w = t >> 6;
    const int lo = lane & 15, hi = lane >> 4;
    const int bb = blockIdx.x, xcd = bb & 7, jj = bb >> 3;
    const int bn = (jj & 7) * 128;
    const int p = (xcd << 3) | (jj >> 3);         // [0,64): (bm-panel, kz)
    const int bm = (p & 31) * 128;
    const int kz = p >> 5;
    float* __restrict__ P = kz ? P1 : P0;
    const int wm = (w >> 1) * 64, wn = (w & 1) * 64;
    const int srow = lane >> 2, skc = lane & 3;

    f32x4 acc[MB][4] = {};
    const int nkt = (K >> 1) >> 5;                // 64
    const int kbeg = kz * nkt;

    STAGE(0, kbeg);
    __syncthreads();
    int cur = 0;
    for (int kt = kbeg; kt < kbeg + nkt; ++kt) {
        if (kt + 1 < kbeg + nkt) STAGE(cur ^ 1, kt + 1);
        const short* as = &As[cur][0];
        const short* bs = &Bs[cur][0];
        short8 af[MB], bfr[4];
#pragma unroll
        for (int mb = 0; mb < MB; ++mb)
            af[mb] = *(const short8*)&as[(wm + mb * 16 + lo) * 32 + hi * 8];
#pragma unroll
        for (int nb = 0; nb < 4; ++nb)
            bfr[nb] = *(const short8*)&bs[(wn + nb * 16 + lo) * 32 + hi * 8];
#pragma unroll
        for (int mb = 0; mb < MB; ++mb)
#pragma unroll
            for (int nb = 0; nb < 4; ++nb)   // swapped operands
                acc[mb][nb] = __builtin_amdgcn_mfma_f32_16x16x32_bf16(bfr[nb], af[mb], acc[mb][nb], 0, 0, 0);
        __syncthreads();
        cur ^= 1;
    }

#pragma unroll
    for (int mb = 0; mb < MB; ++mb)
#pragma unroll
        for (int nb = 0; nb < 4; ++nb) {
            const int row = bm + wm + mb * 16 + lo;
            const int col0 = bn + wn + nb * 16 + hi * 4;
            float4 o4;
            o4.x = acc[mb][nb][0]; o4.y = acc[mb][nb][1];
            o4.z = acc[mb][nb][2]; o4.w = acc[mb][nb][3];
            *(float4*)&P[(size_t)row * Dx + col0] = o4;
        }
}

// ---------------- FFN2 epilogue: out = p0 + p1 + b2 + h1 ----------------
__global__ __launch_bounds__(256) void epi2(const float4* __restrict__ p0,
                                            const float4* __restrict__ p1,
                                            const float4* __restrict__ b2,
                                            const float4* __restrict__ h1,
                                            float4* __restrict__ out) {
    const int i = blockIdx.x * 256 + threadIdx.x;  // 1M float4
    const float4 bv = b2[i & 255];
    const float4 a = p0[i], b = p1[i], h = h1[i];
    float4 o;
    o.x = a.x + b.x + h.x + bv.x;
    o.y = a.y + b.y + h.y + bv.y;
    o.z = a.z + b.z + h.z + bv.z;
    o.w = a.w + b.w + h.w + bv.w;
    out[i] = o;
}

// ---------------- flash attention v6: double-buffered K/V (ONE barrier/tile) ----------------
__global__ __launch_bounds__(256) void attn_fwd6(const short* __restrict__ Q,
                                                 const short* __restrict__ Kg,
                                                 const short* __restrict__ Vtg,
                                                 unsigned short* __restrict__ O) {
    __shared__ alignas(16) short Ks[2][64 * 64];  // [key][dk], XOR-swizzled, double-buffered
    __shared__ alignas(16) short Vs[2][64 * 64];  // [dk][key] (from V^T global), XOR-swizzled
    __shared__ alignas(16) short Pl[4][32 * 64];  // per-wave P [q=32][key=64], XOR-swizzled
    const int t = threadIdx.x, lane = t & 63, w = t >> 6;
    const int bh = blockIdx.x;                    // b*16 + h
    const int b = bh >> 4, h = bh & 15;
    const int q0 = blockIdx.y * 128 + w * 32;
    const int lo = lane & 15, hi = lane >> 4;

    short8 qf[2][2];
#pragma unroll
    for (int mb = 0; mb < 2; ++mb)
#pragma unroll
        for (int kf = 0; kf < 2; ++kf)
            qf[mb][kf] = *(const short8*)&Q[(size_t)(b * Sx + q0 + mb * 16 + lo) * Dx
                                            + h * DKx + kf * 32 + hi * 8];

    f32x4 o_[2][4] = {};
    f32x4 l_acc[2] = {};
    short8 ones;
#pragma unroll
    for (int j = 0; j < 8; ++j) ones[j] = (short)0x3F80;   // bf16 1.0

    const int srow = t >> 2;            // 0..63
    const int scol2 = (t & 3) * 32;     // byte offset within 128B row
    const int swz = (srow & 7) << 4;
    const short* Kbase = Kg + (size_t)(b * Sx) * Dx + h * DKx;
    const short* Vbase = Vtg + (size_t)(bh * 64 + srow) * Sx;
    char* PwB = (char*)&Pl[w][0];

    short8 kr0, kr1, vr0, vr1;
    {   // prefetch tile 0 to regs, write buf 0, single barrier
        const short* kp = Kbase + (size_t)srow * Dx + (t & 3) * 16;
        kr0 = *(const short8*)kp; kr1 = *(const short8*)(kp + 8);
        const short* vp = Vbase + (t & 3) * 16;
        vr0 = *(const short8*)vp; vr1 = *(const short8*)(vp + 8);
        char* KsB = (char*)&Ks[0][0];
        char* VsB = (char*)&Vs[0][0];
        *(short8*)(KsB + ((srow * 128 + scol2) ^ swz)) = kr0;
        *(short8*)(KsB + ((srow * 128 + scol2 + 16) ^ swz)) = kr1;
        *(short8*)(VsB + ((srow * 128 + scol2) ^ swz)) = vr0;
        *(short8*)(VsB + ((srow * 128 + scol2 + 16) ^ swz)) = vr1;
    }
    __syncthreads();

    int cur = 0;
    for (int kt = 0; kt < Sx / 64; ++kt) {
        const bool more = (kt + 1 < Sx / 64);
        if (more) {                      // T14: issue next-tile global loads under compute
            const short* kp = Kbase + (size_t)((kt + 1) * 64 + srow) * Dx + (t & 3) * 16;
            kr0 = *(const short8*)kp; kr1 = *(const short8*)(kp + 8);
            const short* vp = Vbase + (kt + 1) * 64 + (t & 3) * 16;
            vr0 = *(const short8*)vp; vr1 = *(const short8*)(vp + 8);
        }
        char* KsB = (char*)&Ks[cur][0];
        char* VsB = (char*)&Vs[cur][0];

        // S = Q K^T   (rows: mb*16 + hi*4+r, cols: nb*16+lo); Q pre-scaled by CEXP
        f32x4 s[2][4] = {};
        __builtin_amdgcn_s_setprio(1);
#pragma unroll
        for (int nb = 0; nb < 4; ++nb) {
            const int key = nb * 16 + lo;
            const int ksw = (key & 7) << 4;
#pragma unroll
            for (int kf = 0; kf < 2; ++kf) {
                const short8 kfr = *(const short8*)(KsB + ((key * 128 + kf * 64 + hi * 16) ^ ksw));
#pragma unroll
                for (int mb = 0; mb < 2; ++mb)
                    s[mb][nb] = __builtin_amdgcn_mfma_f32_16x16x32_bf16(qf[mb][kf], kfr, s[mb][nb], 0, 0, 0);
            }
        }
        __builtin_amdgcn_s_setprio(0);

        // static softmax: P = exp2(s); truncate to bf16 (num and denom share quantization)
#pragma unroll
        for (int mb = 0; mb < 2; ++mb)
#pragma unroll
            for (int nb = 0; nb < 4; ++nb) {
                const int k = nb * 16 + lo;
#pragma unroll
                for (int r = 0; r < 4; ++r) {
                    const float p = fexp2(s[mb][nb][r]);
                    union { float f; uint32_t u; } cv; cv.f = p;
                    const int qq = mb * 16 + hi * 4 + r;
                    *(short*)(PwB + ((qq * 128 + k * 2) ^ ((qq & 7) << 4))) = (short)(cv.u >> 16);
                }
            }

        // P fragments (A-frag rows: mb*16 + lo) — same-wave LDS, no barrier needed
        short8 pa[2][2];
#pragma unroll
        for (int mb = 0; mb < 2; ++mb)
#pragma unroll
            for (int kc = 0; kc < 2; ++kc)
                pa[mb][kc] = *(const short8*)(PwB + (((mb * 16 + lo) * 128 + kc * 64 + hi * 16) ^ ((lo & 7) << 4)));

        __builtin_amdgcn_s_setprio(1);
        // denominator: l += P @ ones  (row-sum, same C-layout rows as O)
#pragma unroll
        for (int mb = 0; mb < 2; ++mb) {
            l_acc[mb] = __builtin_amdgcn_mfma_f32_16x16x32_bf16(pa[mb][0], ones, l_acc[mb], 0, 0, 0);
            l_acc[mb] = __builtin_amdgcn_mfma_f32_16x16x32_bf16(pa[mb][1], ones, l_acc[mb], 0, 0, 0);
        }

        // O += P V
#pragma unroll
        for (int d = 0; d < 4; ++d) {
            const int vd = d * 16 + lo;
            const int vsw = (vd & 7) << 4;
#pragma unroll
            for (int kc = 0; kc < 2; ++kc) {
                const short8 vf = *(const short8*)(VsB + ((vd * 128 + kc * 64 + hi * 16) ^ vsw));
#pragma unroll
                for (int mb = 0; mb < 2; ++mb)
                    o_[mb][d] = __builtin_amdgcn_mfma_f32_16x16x32_bf16(pa[mb][kc], vf, o_[mb][d], 0, 0, 0);
            }
        }
        __builtin_amdgcn_s_setprio(0);

        if (more) {                      // write next tile into the OTHER buffer (no race)
            char* KsN = (char*)&Ks[cur ^ 1][0];
            char* VsN = (char*)&Vs[cur ^ 1][0];
            *(short8*)(KsN + ((srow * 128 + scol2) ^ swz)) = kr0;
            *(short8*)(KsN + ((srow * 128 + scol2 + 16) ^ swz)) = kr1;
            *(short8*)(VsN + ((srow * 128 + scol2) ^ swz)) = vr0;
            *(short8*)(VsN + ((srow * 128 + scol2 + 16) ^ swz)) = vr1;
        }
        __syncthreads();                 // publishes buf^1; also guards buf-cur reuse
        cur ^= 1;
    }

#pragma unroll
    for (int mb = 0; mb < 2; ++mb)
#pragma unroll
        for (int d = 0; d < 4; ++d)
#pragma unroll
            for (int r = 0; r < 4; ++r) {
                const int qrow = b * Sx + q0 + mb * 16 + hi * 4 + r;
                O[(size_t)qrow * Dx + h * DKx + d * 16 + lo] = f2b(o_[mb][d][r] / l_acc[mb][r]);
            }
}

extern "C" void kernel_launch(void* const* d_in, const int* in_sizes, int n_in,
                              void* d_out, int out_size, void* d_ws, size_t ws_size,
                              hipStream_t stream) {
    const float* x  = (const float*)d_in[0];
    // d_in[1] = src_mask: faithful no-op
    const float* wq = (const float*)d_in[2];
    const float* bq = (const float*)d_in[3];
    const float* wk = (const float*)d_in[4];
    const float* bk = (const float*)d_in[5];
    const float* wv = (const float*)d_in[6];
    const float* bv = (const float*)d_in[7];
    const float* wo = (const float*)d_in[8];
    const float* bo = (const float*)d_in[9];
    const float* w1 = (const float*)d_in[10];
    const float* b1 = (const float*)d_in[11];
    const float* w2 = (const float*)d_in[12];
    const float* b2 = (const float*)d_in[13];
    const float* alpha1 = (const float*)d_in[14];
    const float* bias1  = (const float*)d_in[15];
    const float* alpha2 = (const float*)d_in[16];
    const float* bias2  = (const float*)d_in[17];
    float* out = (float*)d_out;

    short* ws   = (short*)d_ws;
    short* wqkv = ws;                         // [3072][1024] bf16
    short* wob  = wqkv + 3145728;             // [1024][1024]
    short* w1b  = wob  + 1048576;             // [4096][1024]
    short* w2b  = w1b  + 4194304;             // [1024][4096]
    short* n1   = w2b  + 4194304;             // [4096][1024] bf16 (aliased: n1 / ao / n2 / p0-lo)
    short* Qb   = n1   + 4194304;             // [4096][1024]  (p0-hi)
    short* Kb   = Qb   + 4194304;             // [4096][1024]  (p1-lo)
    short* Vt   = Kb   + 4194304;             // [2048][2048]  V^T per (b,h)  (p1-hi)
    short* f1   = Vt   + 4194304;             // [4096][4096]
    float* h1   = (float*)(f1 + 16777216);    // [4096][1024] f32
    float* bqkv = (float*)((char*)h1 + ((size_t)Mx * Dx * 4));   // [3072] f32
    short* ao = n1;   // attn out reuses n1 (dead after QKV GEMM)
    short* n2 = n1;   // LN2 out reuses it again (ao dead after O-proj)
    float* p0 = (float*)n1;   // FFN2 partial 0: n1+Qb region (16 MB), dead after FFN1
    float* p1 = (float*)Kb;   // FFN2 partial 1: Kb+Vt region (16 MB), dead after attn

    conv_all<<<12291, 256, 0, stream>>>((const float4*)wq, (const float4*)wk,
                                        (const float4*)wv, (const float4*)wo,
                                        (const float4*)w1, (const float4*)w2,
                                        (const float4*)bq, (const float4*)bk,
                                        (const float4*)bv,
                                        (ushort4v*)wqkv, (ushort4v*)wob,
                                        (ushort4v*)w1b, (ushort4v*)w2b,
                                        (float4*)bqkv);

    layernorm_k<<<Mx, 256, 0, stream>>>(x, alpha1, bias1, (unsigned short*)n1);

    // fused QKV projection: 256^2 8-wave 2-phase, N = 3072, XCD-grouped (nbn=12, rpx=2)
    gemm256<2><<<192, 512, 0, stream>>>(n1, wqkv, bqkv, nullptr,
                                        Mx, 3072, Dx, 12, 2,
                                        (unsigned short*)Qb, (unsigned short*)Kb,
                                        (unsigned short*)Vt);

    attn_fwd6<<<dim3(32, 16), 256, 0, stream>>>(Qb, Kb, Vt, (unsigned short*)ao);

    // O-projection + residual(x) -> h1 (f32), XCD-grouped 1D grid 512
    gemm2<64><<<512, 256, 0, stream>>>(ao, wob, bo, x, h1, Mx, Dx, Dx);

    layernorm_k<<<Mx, 256, 0, stream>>>(h1, alpha2, bias2, (unsigned short*)n2);

    // FFN1: [4096,1024] x [4096,1024]^T -> bf16 f1 (256^2 8-wave, nbn=16, rpx=2)
    gemm256<0><<<256, 512, 0, stream>>>(n2, w1b, b1, f1,
                                        Mx, DFFx, Dx, 16, 2, nullptr, nullptr, nullptr);

    // FFN2: split-K=2 partials (XCD-grouped), then fused epilogue with bias+residual
    gemmsk<<<512, 256, 0, stream>>>(f1, w2b, p0, p1, DFFx);
    epi2<<<4096, 256, 0, stream>>>((const float4*)p0, (const float4*)p1,
                                   (const float4*)b2, (const float4*)h1, (float4*)out);
}

// Round 10
// 355.023 us; speedup vs baseline: 1.0648x; 1.0648x over previous
//
#include <hip/hip_runtime.h>
#include <stdint.h>

#define Bx   2
#define Sx   2048
#define Dx   1024
#define Hx   16
#define DKx  64
#define DFFx 4096
#define Mx   4096   // B*S

#define CEXP 0.18033688011112042f   // log2(e)/sqrt(64), folded into Q at QKV epilogue

typedef __attribute__((ext_vector_type(8))) short short8;
typedef __attribute__((ext_vector_type(4))) float f32x4;
typedef __attribute__((ext_vector_type(4))) unsigned short ushort4v;

__device__ __forceinline__ unsigned short f2b(float f) {
    union { float f; uint32_t u; } v; v.f = f;
    uint32_t u = v.u;
    u += 0x7fffu + ((u >> 16) & 1u);   // RNE
    return (unsigned short)(u >> 16);
}

__device__ __forceinline__ float fexp2(float x) {
#if __has_builtin(__builtin_amdgcn_exp2f)
    return __builtin_amdgcn_exp2f(x);
#else
    return exp2f(x);
#endif
}

// ---------------- fused weight convert (6 weights) + QKV bias concat ----------------
__global__ __launch_bounds__(256) void conv_all(
    const float4* __restrict__ wq, const float4* __restrict__ wk,
    const float4* __restrict__ wv, const float4* __restrict__ wo,
    const float4* __restrict__ w1, const float4* __restrict__ w2,
    const float4* __restrict__ bq, const float4* __restrict__ bk,
    const float4* __restrict__ bv,
    ushort4v* __restrict__ dqkv, ushort4v* __restrict__ dwo,
    ushort4v* __restrict__ d1, ushort4v* __restrict__ d2,
    float4* __restrict__ dbias) {
    const int i = blockIdx.x * 256 + threadIdx.x;
    const int S4 = 1 << 18;                    // 1024*1024/4
    if (i < 4 * S4) {
        const float4* s; ushort4v* d;
        if (i < S4)          { s = wq + i;            d = dqkv + i; }
        else if (i < 2 * S4) { s = wk + (i - S4);     d = dqkv + i; }
        else if (i < 3 * S4) { s = wv + (i - 2 * S4); d = dqkv + i; }
        else                 { s = wo + (i - 3 * S4); d = dwo + (i - 3 * S4); }
        const float4 v = *s;
        ushort4v o; o.x = f2b(v.x); o.y = f2b(v.y); o.z = f2b(v.z); o.w = f2b(v.w);
        *d = o;
    } else if (i < 8 * S4) {
        const float4 v = w1[i - 4 * S4];
        ushort4v o; o.x = f2b(v.x); o.y = f2b(v.y); o.z = f2b(v.z); o.w = f2b(v.w);
        d1[i - 4 * S4] = o;
    } else if (i < 12 * S4) {
        const float4 v = w2[i - 8 * S4];
        ushort4v o; o.x = f2b(v.x); o.y = f2b(v.y); o.z = f2b(v.z); o.w = f2b(v.w);
        d2[i - 8 * S4] = o;
    } else if (i < 12 * S4 + 768) {
        const int jn = i - 12 * S4;
        dbias[jn] = (jn < 256) ? bq[jn] : (jn < 512 ? bk[jn - 256] : bv[jn - 512]);
    }
}

// ---------------- LayerNorm: ddof=1, alpha*(x-mean)/(std+eps)+bias ----------------
__global__ __launch_bounds__(256) void layernorm_k(const float* __restrict__ x,
                                                   const float* __restrict__ alpha,
                                                   const float* __restrict__ beta,
                                                   unsigned short* __restrict__ out) {
    __shared__ float red[8];
    const int row = blockIdx.x;
    const int t = threadIdx.x, lane = t & 63, w = t >> 6;
    float4 v = ((const float4*)(x + (size_t)row * Dx))[t];
    float s = v.x + v.y + v.z + v.w;
    float q = v.x*v.x + v.y*v.y + v.z*v.z + v.w*v.w;
#pragma unroll
    for (int off = 1; off < 64; off <<= 1) {
        s += __shfl_xor(s, off);
        q += __shfl_xor(q, off);
    }
    if (lane == 0) { red[w] = s; red[4 + w] = q; }
    __syncthreads();
    s = red[0] + red[1] + red[2] + red[3];
    q = red[4] + red[5] + red[6] + red[7];
    const float mean = s * (1.0f / Dx);
    float var = (q - (float)Dx * mean * mean) * (1.0f / (Dx - 1));
    var = fmaxf(var, 0.0f);
    const float inv = alpha[0] / (sqrtf(var) + 1e-5f);
    const float bb = beta[0];
    ushort4v o;
    o.x = f2b((v.x - mean) * inv + bb);
    o.y = f2b((v.y - mean) * inv + bb);
    o.z = f2b((v.z - mean) * inv + bb);
    o.w = f2b((v.w - mean) * inv + bb);
    *(ushort4v*)(out + (size_t)row * Dx + t * 4) = o;
}

#define GLDS(gp, lp) __builtin_amdgcn_global_load_lds( \
    (const __attribute__((address_space(1))) unsigned int*)(gp), \
    (__attribute__((address_space(3))) unsigned int*)(lp), 16, 0, 0)

#define STAGE(buf, kt) do {                                                     \
    const int k0_ = (kt) << 5;                                                  \
    _Pragma("unroll")                                                           \
    for (int i_ = 0; i_ < MB/2; ++i_) {                                         \
      const int ca_ = (MB==4) ? (w*2 + i_) : w;                                 \
      GLDS(A + (size_t)(bm + ca_*16 + srow)*K + k0_ + skc*8, &As[buf][ca_*512]);\
    }                                                                           \
    _Pragma("unroll")                                                           \
    for (int i_ = 0; i_ < 2; ++i_) {                                            \
      const int cb_ = w*2 + i_;                                                 \
      GLDS(W + (size_t)(bn + cb_*16 + srow)*K + k0_ + skc*8, &Bs[buf][cb_*512]);\
    }                                                                           \
  } while (0)

// ---------------- O-proj GEMM: BM=64, 1D XCD-grouped grid of 512 ----------------
// out f32 = A*W^T + bias + res
template<int BM>
__global__ __launch_bounds__(256) void gemm2(const short* __restrict__ A,
                                             const short* __restrict__ W,
                                             const float* __restrict__ bias,
                                             const float* __restrict__ res,
                                             float* __restrict__ Cout,
                                             int M, int N, int K) {
    constexpr int MB = BM / 32;
    __shared__ alignas(16) short As[2][BM * 32];
    __shared__ alignas(16) short Bs[2][128 * 32];
    const int t = threadIdx.x, lane = t & 63, w = t >> 6;
    // XCD-grouped: 8 bn-blocks sharing an A-panel land on one XCD
    const int bb = blockIdx.x, xcd = bb & 7, jj = bb >> 3;
    const int bn = (jj & 7) * 128;
    const int bm = (xcd * 8 + (jj >> 3)) * BM;
    const int wm = (w >> 1) * (BM / 2), wn = (w & 1) * 64;
    const int srow = lane >> 2, skc = lane & 3;

    f32x4 acc[MB][4] = {};
    const int nkt = K >> 5;

    STAGE(0, 0);
    __syncthreads();
    int cur = 0;
    for (int kt = 0; kt < nkt; ++kt) {
        if (kt + 1 < nkt) STAGE(cur ^ 1, kt + 1);
        const short* as = &As[cur][0];
        const short* bs = &Bs[cur][0];
        short8 af[MB], bfr[4];
#pragma unroll
        for (int mb = 0; mb < MB; ++mb)
            af[mb] = *(const short8*)&as[(wm + mb * 16 + (lane & 15)) * 32 + (lane >> 4) * 8];
#pragma unroll
        for (int nb = 0; nb < 4; ++nb)
            bfr[nb] = *(const short8*)&bs[(wn + nb * 16 + (lane & 15)) * 32 + (lane >> 4) * 8];
#pragma unroll
        for (int mb = 0; mb < MB; ++mb)
#pragma unroll
            for (int nb = 0; nb < 4; ++nb)
                acc[mb][nb] = __builtin_amdgcn_mfma_f32_16x16x32_bf16(af[mb], bfr[nb], acc[mb][nb], 0, 0, 0);
        __syncthreads();
        cur ^= 1;
    }

    const int r0 = (lane >> 4) * 4, c0 = lane & 15;
#pragma unroll
    for (int mb = 0; mb < MB; ++mb)
#pragma unroll
        for (int nb = 0; nb < 4; ++nb) {
            const int col = bn + wn + nb * 16 + c0;
            const float bv = bias[col];
            const int row0 = bm + wm + mb * 16 + r0;
#pragma unroll
            for (int r = 0; r < 4; ++r) {
                const size_t idx = (size_t)(row0 + r) * N + col;
                Cout[idx] = acc[mb][nb][r] + bv + res[idx];
            }
        }
}

// ---------------- m97-style 128x128 4-wave 2-phase GEMM, 1D XCD-grouped grid ----------------
// MODE 0: bf16 out. MODE 2: QKV split (Q scaled by CEXP, K row-major; V -> V^T layout).
template<int MODE>
__global__ __launch_bounds__(256) void gemm128(const short* __restrict__ A,
                                               const short* __restrict__ W,
                                               const float* __restrict__ bias,
                                               void* __restrict__ Cout,
                                               int N, int K,
                                               unsigned short* __restrict__ Qout,
                                               unsigned short* __restrict__ Kout,
                                               unsigned short* __restrict__ Vout) {
    constexpr int MB = 4;
    __shared__ alignas(16) short As[2][128 * 32];
    __shared__ alignas(16) short Bs[2][128 * 32];
    const int t = threadIdx.x, lane = t & 63, w = t >> 6;
    // XCD grouping: g = xcd*bpx + j; bn-major chunks so each XCD owns whole B panels
    const int bb = blockIdx.x, bpx = gridDim.x >> 3;
    const int g = (bb & 7) * bpx + (bb >> 3);
    const int bn = (g >> 5) * 128;        // nbm = 32 fixed (M = 4096)
    const int bm = (g & 31) * 128;
    const int wm = (w >> 1) * 64, wn = (w & 1) * 64;
    const int srow = lane >> 2, skc = lane & 3;

    f32x4 acc[MB][4] = {};
    const int nkt = K >> 5;

    STAGE(0, 0);
    __syncthreads();
    int cur = 0;
    for (int kt = 0; kt < nkt; ++kt) {
        if (kt + 1 < nkt) STAGE(cur ^ 1, kt + 1);
        const short* as = &As[cur][0];
        const short* bs = &Bs[cur][0];
        short8 af[MB], bfr[4];
#pragma unroll
        for (int mb = 0; mb < MB; ++mb)
            af[mb] = *(const short8*)&as[(wm + mb * 16 + (lane & 15)) * 32 + (lane >> 4) * 8];
#pragma unroll
        for (int nb = 0; nb < 4; ++nb)
            bfr[nb] = *(const short8*)&bs[(wn + nb * 16 + (lane & 15)) * 32 + (lane >> 4) * 8];
#pragma unroll
        for (int mb = 0; mb < MB; ++mb)
#pragma unroll
            for (int nb = 0; nb < 4; ++nb)
                acc[mb][nb] = __builtin_amdgcn_mfma_f32_16x16x32_bf16(af[mb], bfr[nb], acc[mb][nb], 0, 0, 0);
        __syncthreads();
        cur ^= 1;
    }

    const int r0 = (lane >> 4) * 4, c0 = lane & 15;
#pragma unroll
    for (int mb = 0; mb < MB; ++mb)
#pragma unroll
        for (int nb = 0; nb < 4; ++nb) {
            const int col = bn + wn + nb * 16 + c0;
            const float bv = bias[col];
            const int row0 = bm + wm + mb * 16 + r0;
            if (MODE == 0) {
#pragma unroll
                for (int r = 0; r < 4; ++r)
                    ((unsigned short*)Cout)[(size_t)(row0 + r) * N + col] = f2b(acc[mb][nb][r] + bv);
            } else {
                if (col < 1024) {          // Q, pre-scaled by CEXP (softmax fold)
#pragma unroll
                    for (int r = 0; r < 4; ++r)
                        Qout[(size_t)(row0 + r) * 1024 + col] = f2b((acc[mb][nb][r] + bv) * CEXP);
                } else if (col < 2048) {
#pragma unroll
                    for (int r = 0; r < 4; ++r)
                        Kout[(size_t)(row0 + r) * 1024 + (col - 1024)] = f2b(acc[mb][nb][r] + bv);
                } else {
                    const int dk = col - 2048, hh = dk >> 6, dlo = dk & 63;
                    const int bbv = row0 >> 11, s0 = row0 & 2047;
                    const int vrow = (bbv * 16 + hh) * 64 + dlo;
                    ushort4v pv;
                    pv.x = f2b(acc[mb][nb][0] + bv);
                    pv.y = f2b(acc[mb][nb][1] + bv);
                    pv.z = f2b(acc[mb][nb][2] + bv);
                    pv.w = f2b(acc[mb][nb][3] + bv);
                    *(ushort4v*)&Vout[(size_t)vrow * Sx + s0] = pv;
                }
            }
        }
}

// ---------------- FFN2 split-K GEMM: 128x128, KZ=2, XCD-grouped 1D grid of 512 ----------------
__global__ __launch_bounds__(256) void gemmsk(const short* __restrict__ A,
                                              const short* __restrict__ W,
                                              float* __restrict__ P0,
                                              float* __restrict__ P1,
                                              int K) {
    constexpr int MB = 4;
    __shared__ alignas(16) short As[2][128 * 32];
    __shared__ alignas(16) short Bs[2][128 * 32];
    const int t = threadIdx.x, lane = t & 63, w = t >> 6;
    const int bb = blockIdx.x, xcd = bb & 7, jj = bb >> 3;
    const int bn = (jj & 7) * 128;
    const int p = (xcd << 3) | (jj >> 3);         // [0,64): (bm-panel, kz)
    const int bm = (p & 31) * 128;
    const int kz = p >> 5;
    float* __restrict__ P = kz ? P1 : P0;
    const int wm = (w >> 1) * 64, wn = (w & 1) * 64;
    const int srow = lane >> 2, skc = lane & 3;

    f32x4 acc[MB][4] = {};
    const int nkt = (K >> 1) >> 5;                // 64
    const int kbeg = kz * nkt;

    STAGE(0, kbeg);
    __syncthreads();
    int cur = 0;
    for (int kt = kbeg; kt < kbeg + nkt; ++kt) {
        if (kt + 1 < kbeg + nkt) STAGE(cur ^ 1, kt + 1);
        const short* as = &As[cur][0];
        const short* bs = &Bs[cur][0];
        short8 af[MB], bfr[4];
#pragma unroll
        for (int mb = 0; mb < MB; ++mb)
            af[mb] = *(const short8*)&as[(wm + mb * 16 + (lane & 15)) * 32 + (lane >> 4) * 8];
#pragma unroll
        for (int nb = 0; nb < 4; ++nb)
            bfr[nb] = *(const short8*)&bs[(wn + nb * 16 + (lane & 15)) * 32 + (lane >> 4) * 8];
#pragma unroll
        for (int mb = 0; mb < MB; ++mb)
#pragma unroll
            for (int nb = 0; nb < 4; ++nb)
                acc[mb][nb] = __builtin_amdgcn_mfma_f32_16x16x32_bf16(af[mb], bfr[nb], acc[mb][nb], 0, 0, 0);
        __syncthreads();
        cur ^= 1;
    }

    const int r0 = (lane >> 4) * 4, c0 = lane & 15;
#pragma unroll
    for (int mb = 0; mb < MB; ++mb)
#pragma unroll
        for (int nb = 0; nb < 4; ++nb) {
            const int col = bn + wn + nb * 16 + c0;
            const int row0 = bm + wm + mb * 16 + r0;
#pragma unroll
            for (int r = 0; r < 4; ++r)
                P[(size_t)(row0 + r) * Dx + col] = acc[mb][nb][r];
        }
}

// ---------------- FFN2 epilogue: out = p0 + p1 + b2 + h1 ----------------
__global__ __launch_bounds__(256) void epi2(const float4* __restrict__ p0,
                                            const float4* __restrict__ p1,
                                            const float4* __restrict__ b2,
                                            const float4* __restrict__ h1,
                                            float4* __restrict__ out) {
    const int i = blockIdx.x * 256 + threadIdx.x;  // 1M float4
    const float4 bv = b2[i & 255];
    const float4 a = p0[i], b = p1[i], h = h1[i];
    float4 o;
    o.x = a.x + b.x + h.x + bv.x;
    o.y = a.y + b.y + h.y + bv.y;
    o.z = a.z + b.z + h.z + bv.z;
    o.w = a.w + b.w + h.w + bv.w;
    out[i] = o;
}

// ---------------- flash attention v7: dbuf K/V + swapped QK^T (vectorized P-write) ----------------
__global__ __launch_bounds__(256) void attn_fwd7(const short* __restrict__ Q,
                                                 const short* __restrict__ Kg,
                                                 const short* __restrict__ Vtg,
                                                 unsigned short* __restrict__ O) {
    __shared__ alignas(16) short Ks[2][64 * 64];  // [key][dk], XOR-swizzled, double-buffered
    __shared__ alignas(16) short Vs[2][64 * 64];  // [dk][key] (from V^T global), XOR-swizzled
    __shared__ alignas(16) short Pl[4][32 * 64];  // per-wave P [q=32][key=64], XOR-swizzled
    const int t = threadIdx.x, lane = t & 63, w = t >> 6;
    const int bh = blockIdx.x;                    // b*16 + h
    const int b = bh >> 4, h = bh & 15;
    const int q0 = blockIdx.y * 128 + w * 32;
    const int lo = lane & 15, hi = lane >> 4;

    short8 qf[2][2];
#pragma unroll
    for (int mb = 0; mb < 2; ++mb)
#pragma unroll
        for (int kf = 0; kf < 2; ++kf)
            qf[mb][kf] = *(const short8*)&Q[(size_t)(b * Sx + q0 + mb * 16 + lo) * Dx
                                            + h * DKx + kf * 32 + hi * 8];

    f32x4 o_[2][4] = {};
    f32x4 l_acc[2] = {};
    short8 ones;
#pragma unroll
    for (int j = 0; j < 8; ++j) ones[j] = (short)0x3F80;   // bf16 1.0

    const int srow = t >> 2;            // 0..63
    const int scol2 = (t & 3) * 32;     // byte offset within 128B row
    const int swz = (srow & 7) << 4;
    const short* Kbase = Kg + (size_t)(b * Sx) * Dx + h * DKx;
    const short* Vbase = Vtg + (size_t)(bh * 64 + srow) * Sx;
    char* PwB = (char*)&Pl[w][0];

    short8 kr0, kr1, vr0, vr1;
    {   // prefetch tile 0 to regs, write buf 0, single barrier
        const short* kp = Kbase + (size_t)srow * Dx + (t & 3) * 16;
        kr0 = *(const short8*)kp; kr1 = *(const short8*)(kp + 8);
        const short* vp = Vbase + (t & 3) * 16;
        vr0 = *(const short8*)vp; vr1 = *(const short8*)(vp + 8);
        char* KsB = (char*)&Ks[0][0];
        char* VsB = (char*)&Vs[0][0];
        *(short8*)(KsB + ((srow * 128 + scol2) ^ swz)) = kr0;
        *(short8*)(KsB + ((srow * 128 + scol2 + 16) ^ swz)) = kr1;
        *(short8*)(VsB + ((srow * 128 + scol2) ^ swz)) = vr0;
        *(short8*)(VsB + ((srow * 128 + scol2 + 16) ^ swz)) = vr1;
    }
    __syncthreads();

    int cur = 0;
    for (int kt = 0; kt < Sx / 64; ++kt) {
        const bool more = (kt + 1 < Sx / 64);
        if (more) {                      // T14: issue next-tile global loads under compute
            const short* kp = Kbase + (size_t)((kt + 1) * 64 + srow) * Dx + (t & 3) * 16;
            kr0 = *(const short8*)kp; kr1 = *(const short8*)(kp + 8);
            const short* vp = Vbase + (kt + 1) * 64 + (t & 3) * 16;
            vr0 = *(const short8*)vp; vr1 = *(const short8*)(vp + 8);
        }
        char* KsB = (char*)&Ks[cur][0];
        char* VsB = (char*)&Vs[cur][0];

        // S^T = K Q^T  (swapped operands: rows=key kb*16+hi*4+r, cols=q mb*16+lo)
        // Q pre-scaled by CEXP at QKV epilogue.
        f32x4 st[4][2] = {};
        __builtin_amdgcn_s_setprio(1);
#pragma unroll
        for (int kb = 0; kb < 4; ++kb) {
            const int key = kb * 16 + lo;
            const int ksw = (key & 7) << 4;
#pragma unroll
            for (int kf = 0; kf < 2; ++kf) {
                const short8 kfr = *(const short8*)(KsB + ((key * 128 + kf * 64 + hi * 16) ^ ksw));
#pragma unroll
                for (int mb = 0; mb < 2; ++mb)
                    st[kb][mb] = __builtin_amdgcn_mfma_f32_16x16x32_bf16(kfr, qf[mb][kf], st[kb][mb], 0, 0, 0);
            }
        }
        __builtin_amdgcn_s_setprio(0);

        // static softmax: P = exp2(s); truncate to bf16.
        // Lane holds 4 CONSECUTIVE keys per (kb,mb) -> pack & ds_write_b64 (8 stores vs 32)
#pragma unroll
        for (int mb = 0; mb < 2; ++mb) {
            const int q = mb * 16 + lo;
            const int qsw = (q & 7) << 4;
            char* rowp = PwB + q * 128;
#pragma unroll
            for (int kb = 0; kb < 4; ++kb) {
                ushort4v pk;
#pragma unroll
                for (int r = 0; r < 4; ++r) {
                    const float p = fexp2(st[kb][mb][r]);
                    union { float f; uint32_t u; } cv; cv.f = p;
                    pk[r] = (unsigned short)(cv.u >> 16);
                }
                *(ushort4v*)(rowp + ((kb * 32 + hi * 8) ^ qsw)) = pk;
            }
        }

        // P fragments (A-frag rows: mb*16 + lo) — same-wave LDS, no barrier needed
        short8 pa[2][2];
#pragma unroll
        for (int mb = 0; mb < 2; ++mb)
#pragma unroll
            for (int kc = 0; kc < 2; ++kc)
                pa[mb][kc] = *(const short8*)(PwB + (((mb * 16 + lo) * 128 + kc * 64 + hi * 16) ^ ((lo & 7) << 4)));

        __builtin_amdgcn_s_setprio(1);
        // denominator: l += P @ ones  (row-sum, same C-layout rows as O)
#pragma unroll
        for (int mb = 0; mb < 2; ++mb) {
            l_acc[mb] = __builtin_amdgcn_mfma_f32_16x16x32_bf16(pa[mb][0], ones, l_acc[mb], 0, 0, 0);
            l_acc[mb] = __builtin_amdgcn_mfma_f32_16x16x32_bf16(pa[mb][1], ones, l_acc[mb], 0, 0, 0);
        }

        // O += P V
#pragma unroll
        for (int d = 0; d < 4; ++d) {
            const int vd = d * 16 + lo;
            const int vsw = (vd & 7) << 4;
#pragma unroll
            for (int kc = 0; kc < 2; ++kc) {
                const short8 vf = *(const short8*)(VsB + ((vd * 128 + kc * 64 + hi * 16) ^ vsw));
#pragma unroll
                for (int mb = 0; mb < 2; ++mb)
                    o_[mb][d] = __builtin_amdgcn_mfma_f32_16x16x32_bf16(pa[mb][kc], vf, o_[mb][d], 0, 0, 0);
            }
        }
        __builtin_amdgcn_s_setprio(0);

        if (more) {                      // write next tile into the OTHER buffer (no race)
            char* KsN = (char*)&Ks[cur ^ 1][0];
            char* VsN = (char*)&Vs[cur ^ 1][0];
            *(short8*)(KsN + ((srow * 128 + scol2) ^ swz)) = kr0;
            *(short8*)(KsN + ((srow * 128 + scol2 + 16) ^ swz)) = kr1;
            *(short8*)(VsN + ((srow * 128 + scol2) ^ swz)) = vr0;
            *(short8*)(VsN + ((srow * 128 + scol2 + 16) ^ swz)) = vr1;
        }
        __syncthreads();                 // publishes buf^1; also guards buf-cur reuse
        cur ^= 1;
    }

#pragma unroll
    for (int mb = 0; mb < 2; ++mb)
#pragma unroll
        for (int d = 0; d < 4; ++d)
#pragma unroll
            for (int r = 0; r < 4; ++r) {
                const int qrow = b * Sx + q0 + mb * 16 + hi * 4 + r;
                O[(size_t)qrow * Dx + h * DKx + d * 16 + lo] = f2b(o_[mb][d][r] / l_acc[mb][r]);
            }
}

extern "C" void kernel_launch(void* const* d_in, const int* in_sizes, int n_in,
                              void* d_out, int out_size, void* d_ws, size_t ws_size,
                              hipStream_t stream) {
    const float* x  = (const float*)d_in[0];
    // d_in[1] = src_mask: faithful no-op
    const float* wq = (const float*)d_in[2];
    const float* bq = (const float*)d_in[3];
    const float* wk = (const float*)d_in[4];
    const float* bk = (const float*)d_in[5];
    const float* wv = (const float*)d_in[6];
    const float* bv = (const float*)d_in[7];
    const float* wo = (const float*)d_in[8];
    const float* bo = (const float*)d_in[9];
    const float* w1 = (const float*)d_in[10];
    const float* b1 = (const float*)d_in[11];
    const float* w2 = (const float*)d_in[12];
    const float* b2 = (const float*)d_in[13];
    const float* alpha1 = (const float*)d_in[14];
    const float* bias1  = (const float*)d_in[15];
    const float* alpha2 = (const float*)d_in[16];
    const float* bias2  = (const float*)d_in[17];
    float* out = (float*)d_out;

    short* ws   = (short*)d_ws;
    short* wqkv = ws;                         // [3072][1024] bf16
    short* wob  = wqkv + 3145728;             // [1024][1024]
    short* w1b  = wob  + 1048576;             // [4096][1024]
    short* w2b  = w1b  + 4194304;             // [1024][4096]
    short* n1   = w2b  + 4194304;             // [4096][1024] bf16 (aliased: n1 / ao / n2 / p0-lo)
    short* Qb   = n1   + 4194304;             // [4096][1024]  (p0-hi)
    short* Kb   = Qb   + 4194304;             // [4096][1024]  (p1-lo)
    short* Vt   = Kb   + 4194304;             // [2048][2048]  V^T per (b,h)  (p1-hi)
    short* f1   = Vt   + 4194304;             // [4096][4096]
    float* h1   = (float*)(f1 + 16777216);    // [4096][1024] f32
    float* bqkv = (float*)((char*)h1 + ((size_t)Mx * Dx * 4));   // [3072] f32
    short* ao = n1;   // attn out reuses n1 (dead after QKV GEMM)
    short* n2 = n1;   // LN2 out reuses it again (ao dead after O-proj)
    float* p0 = (float*)n1;   // FFN2 partial 0: n1+Qb region (16 MB), dead after FFN1
    float* p1 = (float*)Kb;   // FFN2 partial 1: Kb+Vt region (16 MB), dead after attn

    conv_all<<<12291, 256, 0, stream>>>((const float4*)wq, (const float4*)wk,
                                        (const float4*)wv, (const float4*)wo,
                                        (const float4*)w1, (const float4*)w2,
                                        (const float4*)bq, (const float4*)bk,
                                        (const float4*)bv,
                                        (ushort4v*)wqkv, (ushort4v*)wob,
                                        (ushort4v*)w1b, (ushort4v*)w2b,
                                        (float4*)bqkv);

    layernorm_k<<<Mx, 256, 0, stream>>>(x, alpha1, bias1, (unsigned short*)n1);

    // fused QKV projection: m97 128^2, N = 3072, 768 blocks XCD-grouped
    gemm128<2><<<768, 256, 0, stream>>>(n1, wqkv, bqkv, nullptr, 3072, Dx,
                                        (unsigned short*)Qb, (unsigned short*)Kb,
                                        (unsigned short*)Vt);

    attn_fwd7<<<dim3(32, 16), 256, 0, stream>>>(Qb, Kb, Vt, (unsigned short*)ao);

    // O-projection + residual(x) -> h1 (f32), XCD-grouped 1D grid 512
    gemm2<64><<<512, 256, 0, stream>>>(ao, wob, bo, x, h1, Mx, Dx, Dx);

    layernorm_k<<<Mx, 256, 0, stream>>>(h1, alpha2, bias2, (unsigned short*)n2);

    // FFN1: [4096,1024] x [4096,1024]^T -> bf16 f1 (m97 128^2, 1024 blocks XCD-grouped)
    gemm128<0><<<1024, 256, 0, stream>>>(n2, w1b, b1, f1, DFFx, Dx,
                                         nullptr, nullptr, nullptr);

    // FFN2: split-K=2 partials (XCD-grouped), then fused epilogue with bias+residual
    gemmsk<<<512, 256, 0, stream>>>(f1, w2b, p0, p1, DFFx);
    epi2<<<4096, 256, 0, stream>>>((const float4*)p0, (const float4*)p1,
                                   (const float4*)b2, (const float4*)h1, (float4*)out);
}